// Round 15
// baseline (408.686 us; speedup 1.0000x reference)
//
#include <hip/hip_runtime.h>
#include <math.h>

#define NEXP 8
#define CAP 2048
#define NTOK 4096
#define DDIM 1024
#define FDIM 4096

typedef __bf16 bf16x8 __attribute__((ext_vector_type(8)));
typedef float f32x4 __attribute__((ext_vector_type(4)));
typedef unsigned short u16x8 __attribute__((ext_vector_type(8)));

__device__ __forceinline__ unsigned short f2bf(float f) {
    unsigned int u = __float_as_uint(f);
    u += 0x7FFFu + ((u >> 16) & 1u);   // RNE
    return (unsigned short)(u >> 16);
}
__device__ __forceinline__ float bf2f(unsigned short h) {
    return __uint_as_float(((unsigned int)h) << 16);
}

__device__ __forceinline__ void gld_lds16(const void* g, void* l) {
    __builtin_amdgcn_global_load_lds((const __attribute__((address_space(1))) void*)g,
                                     (__attribute__((address_space(3))) void*)l, 16, 0, 0);
}

// ---------------- transpose + f32->bf16 convert:  in [E][R][C] f32 -> out [E][C][R] bf16
__global__ __launch_bounds__(256) void transpose_cvt64(const float* __restrict__ in,
                                                       unsigned short* __restrict__ out,
                                                       int R, int C) {
    __shared__ float tile[64][65];
    int e = blockIdx.z;
    const float* ip = in + (size_t)e * R * C;
    unsigned short* op = out + (size_t)e * R * C;
    int c0 = blockIdx.x * 64, r0 = blockIdx.y * 64;
    int t = threadIdx.x;
#pragma unroll
    for (int i = 0; i < 4; i++) {
        int rr = i * 16 + (t >> 4);
        int cc = (t & 15) * 4;
        float4 v = *(const float4*)&ip[(size_t)(r0 + rr) * C + c0 + cc];
        tile[rr][cc] = v.x; tile[rr][cc + 1] = v.y; tile[rr][cc + 2] = v.z; tile[rr][cc + 3] = v.w;
    }
    __syncthreads();
    int c = t >> 2, rb = (t & 3) * 16;
    u16x8 o0, o1;
#pragma unroll
    for (int j = 0; j < 8; j++) o0[j] = f2bf(tile[rb + j][c]);
#pragma unroll
    for (int j = 0; j < 8; j++) o1[j] = f2bf(tile[rb + 8 + j][c]);
    unsigned short* dst = op + (size_t)(c0 + c) * R + r0 + rb;
    *(u16x8*)dst = o0;
    *(u16x8*)(dst + 8) = o1;
}

// ---------------- router: logits = x @ w_g, top-2 + softmax probs. One wave per token.
__global__ __launch_bounds__(256) void router_kernel(const float* __restrict__ x,
                                                     const float* __restrict__ wg,
                                                     int2* __restrict__ e01,
                                                     float2* __restrict__ p01) {
    int wid = threadIdx.x >> 6, lane = threadIdx.x & 63;
    int n = blockIdx.x * 4 + wid;
    float acc[8];
#pragma unroll
    for (int i = 0; i < 8; i++) acc[i] = 0.f;
    const float4* xr = (const float4*)(x + (size_t)n * DDIM);
#pragma unroll
    for (int j = 0; j < 4; j++) {
        float4 xv = xr[j * 64 + lane];
        int base = (j * 64 + lane) * 4;
        float xs[4] = {xv.x, xv.y, xv.z, xv.w};
#pragma unroll
        for (int t = 0; t < 4; t++) {
            const float4* wr = (const float4*)(wg + (size_t)(base + t) * 8);
            float4 w0 = wr[0], w1 = wr[1];
            acc[0] += xs[t] * w0.x; acc[1] += xs[t] * w0.y;
            acc[2] += xs[t] * w0.z; acc[3] += xs[t] * w0.w;
            acc[4] += xs[t] * w1.x; acc[5] += xs[t] * w1.y;
            acc[6] += xs[t] * w1.z; acc[7] += xs[t] * w1.w;
        }
    }
#pragma unroll
    for (int off = 32; off > 0; off >>= 1) {
#pragma unroll
        for (int i = 0; i < 8; i++) acc[i] += __shfl_xor(acc[i], off);
    }
    if (lane == 0) {
        int i0 = 0; float v0 = acc[0];
#pragma unroll
        for (int q = 1; q < 8; q++) { if (acc[q] > v0) { v0 = acc[q]; i0 = q; } }
        int i1 = -1; float v1 = -3.0e38f;
#pragma unroll
        for (int q = 0; q < 8; q++) { if (q != i0 && acc[q] > v1) { v1 = acc[q]; i1 = q; } }
        float ea = expf(v0 - v0), eb = expf(v1 - v0);
        float inv = 1.f / (ea + eb);
        e01[n] = make_int2(i0, i1);
        p01[n] = make_float2(ea * inv, eb * inv);
    }
}

// ---------------- assignment scan: exact reference ranks (all k=0 by token order, then k=1)
__global__ void assign_kernel(const int2* __restrict__ e01, int* __restrict__ counts,
                              int* __restrict__ assign_row, int* __restrict__ tok_slot) {
    int lane = threadIdx.x;   // single wave of 64
    int base[8];
#pragma unroll
    for (int i = 0; i < 8; i++) base[i] = 0;
    unsigned long long below = ((unsigned long long)1 << lane) - 1ull;
    int2 cur = e01[lane];
    for (int pass = 0; pass < 2; ++pass) {
        for (int t = 0; t < NTOK; t += 64) {
            int n = t + lane;
            int2 nxt;
            if (t + 64 < NTOK) nxt = e01[t + 64 + lane];
            else nxt = (pass == 0) ? e01[lane] : make_int2(0, 0);
            int ex = (pass == 0) ? cur.x : cur.y;
            int slot = -1;
#pragma unroll
            for (int q = 0; q < 8; q++) {
                unsigned long long m = __ballot(ex == q);
                if (ex == q) slot = base[q] + __popcll(m & below);
                base[q] += __popcll(m);
            }
            if (slot < CAP) {
                assign_row[ex * CAP + slot] = n;
                tok_slot[2 * n + pass] = slot;
            } else {
                tok_slot[2 * n + pass] = -1;
            }
            cur = nxt;
        }
    }
    if (lane < 8) counts[lane] = base[lane] > CAP ? CAP : base[lane];
}

// ---------------- gather x rows -> xg[e][slot][:] bf16. One wave per slot.
__global__ __launch_bounds__(256) void gather_rows(const float* __restrict__ x,
                                                   const int* __restrict__ assign_row,
                                                   const int* __restrict__ counts,
                                                   unsigned short* __restrict__ xg) {
    int e = blockIdx.y;
    int wid = threadIdx.x >> 6, lane = threadIdx.x & 63;
    int slot = blockIdx.x * 4 + wid;
    if (slot >= counts[e]) return;
    int n = assign_row[e * CAP + slot];
    const float4* src = (const float4*)(x + (size_t)n * DDIM);
    unsigned short* dst = xg + ((size_t)e * CAP + slot) * DDIM;
#pragma unroll
    for (int j = 0; j < 4; j++) {
        float4 v = src[j * 64 + lane];
        ushort4 o;
        o.x = f2bf(v.x); o.y = f2bf(v.y); o.z = f2bf(v.z); o.w = f2bf(v.w);
        *(ushort4*)(dst + (size_t)(j * 64 + lane) * 4) = o;
    }
}

// ---------------- R10-proven 256x256 3-buffer counted-vmcnt bf16 GEMM (both GEMMs):
// C = A[M,K]*Bt[N,K]^T, f32 accum. BK=32, 8 waves (2Mx4N), per-wave 128x64, acc[8][4].
// LDS 3 x 32KB = 96KB (1 block/CU). Counted vmcnt keeps 4-8 loads in flight across
// barriers (pipe never drains) -> staging sustains ~4.5 TB/s at 1 resident block
// (R10 proj measurement). 256^2 tile halves staged bytes vs 128-wide (537 MB/GEMM),
// attacking the measured per-CU VMEM service-rate wall (5.4-6.1 TB/s, R14 analysis).
// Per tile: stage(t+2) -> ds_read buf[t%3] -> 32 MFMA -> vmcnt(4) [retires exactly
// tile t+1; never 0 until wind-down] -> one s_barrier. Buffers mod-3 disjoint.
// Swizzle: 16B chunk c ^= (row>>1)&3 both sides (0 conflicts, R6-R14).
// KC: split-K planes, bf16 output at plane (kc*NEXP+e); GELU for fc epilogue.
template <bool GELU, int KC>
__global__ __launch_bounds__(512, 2) void gemm_pc(const unsigned short* __restrict__ A,
                                                  const unsigned short* __restrict__ Bt,
                                                  unsigned short* __restrict__ Cout,
                                                  const int* __restrict__ counts,
                                                  int Ncols, int Ktot) {
    constexpr int ABYTES = 16384;
    constexpr int BUFB = 32768;
    __shared__ __align__(16) char smem[3 * BUFB];   // 96 KB

    // T1: bijective chunked XCD swizzle (grid sizes are multiples of 8)
    int gx = gridDim.x, gy = gridDim.y;
    int nwg = gx * gy * gridDim.z;
    int flat = blockIdx.x + gx * (blockIdx.y + gy * blockIdx.z);
    int cpx = nwg >> 3;
    int swz = (flat & 7) * cpx + (flat >> 3);
    int gxy = gx * gy;
    int zz = swz / gxy;
    int r2 = swz - zz * gxy;
    int by = r2 / gx;
    int bx = r2 - by * gx;
    int e = zz / KC, kc = zz % KC;

    int cnt = counts[e];
    int row0 = by * 256;
    if (row0 >= cnt) return;
    int col0 = bx * 256;
    const int Ksub = Ktot / KC;
    const int NT = Ksub / 32;

    int tid = threadIdx.x, w = tid >> 6, lane = tid & 63;
    int wm = w >> 2, wn = w & 3;

    const unsigned short* Ab = A + ((size_t)e * CAP + row0) * Ktot + (size_t)kc * Ksub;
    const unsigned short* Bb = Bt + ((size_t)e * Ncols + col0) * Ktot + (size_t)kc * Ksub;

    int kel = (((tid & 3) ^ ((tid >> 3) & 3)) * 8);
    int aoff[8], boff[4];
    int c0 = lane >> 4;
#pragma unroll
    for (int mq = 0; mq < 8; mq++) {
        int row = wm * 128 + mq * 16 + (lane & 15);
        aoff[mq] = row * 64 + ((c0 ^ ((row >> 1) & 3)) << 4);
    }
#pragma unroll
    for (int nq = 0; nq < 4; nq++) {
        int row = wn * 64 + nq * 16 + (lane & 15);
        boff[nq] = row * 64 + ((c0 ^ ((row >> 1) & 3)) << 4);
    }

    auto stage = [&](int tt) {
        int bb = (tt % 3) * BUFB;
        size_t kt = (size_t)tt * 32 + kel;
#pragma unroll
        for (int i = 0; i < 2; i++)
            gld_lds16(Ab + (size_t)(i * 128 + (tid >> 2)) * Ktot + kt, smem + bb + i * 8192 + tid * 16);
#pragma unroll
        for (int i = 0; i < 2; i++)
            gld_lds16(Bb + (size_t)(i * 128 + (tid >> 2)) * Ktot + kt, smem + bb + ABYTES + i * 8192 + tid * 16);
    };

    f32x4 acc[8][4] = {};

    // prologue: stage tiles 0,1 (8 loads/thread); retire tile 0 only -> vmcnt(4)
    stage(0); stage(1);
    asm volatile("s_waitcnt vmcnt(4) lgkmcnt(0)" ::: "memory");
    __builtin_amdgcn_sched_barrier(0);
    __builtin_amdgcn_s_barrier();

    for (int t = 0; t < NT; ++t) {
        const int bb = (t % 3) * BUFB;
        if (t + 2 < NT) stage(t + 2);          // distance-2 prefetch FIRST
        __builtin_amdgcn_sched_barrier(0);
        bf16x8 a[8], b[4];
#pragma unroll
        for (int mq = 0; mq < 8; mq++) a[mq] = *(const bf16x8*)(smem + bb + aoff[mq]);
#pragma unroll
        for (int nq = 0; nq < 4; nq++) b[nq] = *(const bf16x8*)(smem + bb + ABYTES + boff[nq]);
        __builtin_amdgcn_s_setprio(1);
#pragma unroll
        for (int mq = 0; mq < 8; mq++)
#pragma unroll
            for (int nq = 0; nq < 4; nq++)
                acc[mq][nq] = __builtin_amdgcn_mfma_f32_16x16x32_bf16(a[mq], b[nq], acc[mq][nq], 0, 0, 0);
        __builtin_amdgcn_s_setprio(0);
        // counted wait: retire tile t+1 (issued at tile t-1); never 0 mid-loop
        if (t + 2 < NT) asm volatile("s_waitcnt vmcnt(4) lgkmcnt(0)" ::: "memory");
        else            asm volatile("s_waitcnt vmcnt(0) lgkmcnt(0)" ::: "memory");
        __builtin_amdgcn_sched_barrier(0);
        __builtin_amdgcn_s_barrier();
    }

    // epilogue: C/D layout col = lane&15, row = (lane>>4)*4 + j. bf16 out, plane kc.
    unsigned short* Cb = Cout + (((size_t)(kc * NEXP + e) * CAP + row0)) * Ncols + col0;
#pragma unroll
    for (int mq = 0; mq < 8; mq++)
#pragma unroll
        for (int nq = 0; nq < 4; nq++)
#pragma unroll
            for (int j = 0; j < 4; j++) {
                int lr = wm * 128 + mq * 16 + ((lane >> 4) << 2) + j;
                int lc = wn * 64 + nq * 16 + (lane & 15);
                float v = acc[mq][nq][j];
                if constexpr (GELU) {
                    float g = 0.5f * v * (1.0f + erff(v * 0.70710678118654752f));
                    Cb[(size_t)lr * Ncols + lc] = f2bf(g);
                } else {
                    Cb[(size_t)lr * Ncols + lc] = f2bf(v);
                }
            }
}

// ---------------- combine (p0*(pb0+pb1) + p1*(pb0+pb1)) + LayerNorm. pb bf16 split-K partials.
__global__ __launch_bounds__(256) void combine_ln_kernel(const unsigned short* __restrict__ pb,
                                                         const int2* __restrict__ e01,
                                                         const float2* __restrict__ p01,
                                                         const int* __restrict__ tok_slot,
                                                         const float* __restrict__ lnw,
                                                         const float* __restrict__ lnb,
                                                         float* __restrict__ out) {
    const size_t PLANE = (size_t)NEXP * CAP * DDIM;
    int n = blockIdx.x, t = threadIdx.x;
    int2 e = e01[n];
    float2 p = p01[n];
    int s0 = tok_slot[2 * n], s1 = tok_slot[2 * n + 1];
    float o0 = 0.f, o1 = 0.f, o2 = 0.f, o3 = 0.f;
    if (s0 >= 0) {
        size_t base = ((size_t)e.x * CAP + s0) * DDIM;
        ushort4 u0 = ((const ushort4*)(pb + base))[t];
        ushort4 u1 = ((const ushort4*)(pb + PLANE + base))[t];
        o0 += p.x * (bf2f(u0.x) + bf2f(u1.x));
        o1 += p.x * (bf2f(u0.y) + bf2f(u1.y));
        o2 += p.x * (bf2f(u0.z) + bf2f(u1.z));
        o3 += p.x * (bf2f(u0.w) + bf2f(u1.w));
    }
    if (s1 >= 0) {
        size_t base = ((size_t)e.y * CAP + s1) * DDIM;
        ushort4 u0 = ((const ushort4*)(pb + base))[t];
        ushort4 u1 = ((const ushort4*)(pb + PLANE + base))[t];
        o0 += p.y * (bf2f(u0.x) + bf2f(u1.x));
        o1 += p.y * (bf2f(u0.y) + bf2f(u1.y));
        o2 += p.y * (bf2f(u0.z) + bf2f(u1.z));
        o3 += p.y * (bf2f(u0.w) + bf2f(u1.w));
    }
    float s = o0 + o1 + o2 + o3;
    float sq = o0 * o0 + o1 * o1 + o2 * o2 + o3 * o3;
#pragma unroll
    for (int off = 32; off > 0; off >>= 1) {
        s += __shfl_xor(s, off);
        sq += __shfl_xor(sq, off);
    }
    __shared__ float red[8];
    int wid = t >> 6, lane = t & 63;
    if (lane == 0) { red[wid] = s; red[4 + wid] = sq; }
    __syncthreads();
    s = red[0] + red[1] + red[2] + red[3];
    sq = red[4] + red[5] + red[6] + red[7];
    float mu = s * (1.f / DDIM);
    float var = sq * (1.f / DDIM) - mu * mu;
    float inv = rsqrtf(var + 1e-5f);
    const float4 w = ((const float4*)lnw)[t];
    const float4 b = ((const float4*)lnb)[t];
    float4 r;
    r.x = (o0 - mu) * inv * w.x + b.x;
    r.y = (o1 - mu) * inv * w.y + b.y;
    r.z = (o2 - mu) * inv * w.z + b.z;
    r.w = (o3 - mu) * inv * w.w + b.w;
    ((float4*)(out + (size_t)n * DDIM))[t] = r;
}

extern "C" void kernel_launch(void* const* d_in, const int* in_sizes, int n_in,
                              void* d_out, int out_size, void* d_ws, size_t ws_size,
                              hipStream_t stream) {
    const float* x   = (const float*)d_in[0];
    const float* wg  = (const float*)d_in[1];
    const float* cfc = (const float*)d_in[2];
    const float* cpr = (const float*)d_in[3];
    const float* lnw = (const float*)d_in[4];
    const float* lnb = (const float*)d_in[5];
    float* out = (float*)d_out;

    char* ws = (char*)d_ws;
    size_t off = 0;
    auto take = [&](size_t b) {
        char* p = ws + off;
        off += (b + 255) & ~(size_t)255;
        return p;
    };
    // c_fc_t [E][F][D] bf16 (64MB) — dead after fc GEMM; pb [2][E][CAP][D] bf16 (64MB) aliases it
    unsigned short* cfct = (unsigned short*)take((size_t)NEXP * FDIM * DDIM * 2);
    unsigned short* pb = cfct;
    unsigned short* cprt = (unsigned short*)take((size_t)NEXP * DDIM * FDIM * 2); // [E][D][F]
    unsigned short* xg   = (unsigned short*)take((size_t)NEXP * CAP * DDIM * 2);  // [E][CAP][D]
    unsigned short* h    = (unsigned short*)take((size_t)NEXP * CAP * FDIM * 2);  // [E][CAP][F]
    int2*   e01      = (int2*)take(NTOK * sizeof(int2));
    float2* p01      = (float2*)take(NTOK * sizeof(float2));
    int*    tok_slot = (int*)take((size_t)NTOK * 2 * 4);
    int*    assign_row = (int*)take((size_t)NEXP * CAP * 4);
    int*    counts   = (int*)take(256);

    transpose_cvt64<<<dim3(FDIM / 64, DDIM / 64, NEXP), 256, 0, stream>>>(cfc, cfct, DDIM, FDIM);
    transpose_cvt64<<<dim3(DDIM / 64, FDIM / 64, NEXP), 256, 0, stream>>>(cpr, cprt, FDIM, DDIM);
    router_kernel<<<NTOK / 4, 256, 0, stream>>>(x, wg, e01, p01);
    assign_kernel<<<1, 64, 0, stream>>>(e01, counts, assign_row, tok_slot);
    gather_rows<<<dim3(CAP / 4, NEXP), 256, 0, stream>>>(x, assign_row, counts, xg);
    // fc: 256x256, K=1024 (NT=32), counted vmcnt. grid 16x8x8 = 1024 (live ~512).
    gemm_pc<true, 1><<<dim3(FDIM / 256, CAP / 256, NEXP), 512, 0, stream>>>(xg, cfct, h, counts, FDIM, DDIM);
    // proj: 256x256, split-K=2 (Ksub=2048, NT=64), counted vmcnt. grid 4x8x16 = 512 (live ~256).
    gemm_pc<false, 2><<<dim3(DDIM / 256, CAP / 256, NEXP * 2), 512, 0, stream>>>(h, cprt, pb, counts, DDIM, FDIM);
    combine_ln_kernel<<<NTOK, 256, 0, stream>>>(pb, e01, p01, tok_slot, lnw, lnb, out);
}

// Round 16
// 350.718 us; speedup vs baseline: 1.1653x; 1.1653x over previous
//
#include <hip/hip_runtime.h>
#include <math.h>

#define NEXP 8
#define CAP 2048
#define NTOK 4096
#define DDIM 1024
#define FDIM 4096

typedef __bf16 bf16x8 __attribute__((ext_vector_type(8)));
typedef float f32x4 __attribute__((ext_vector_type(4)));
typedef unsigned short u16x8 __attribute__((ext_vector_type(8)));

__device__ __forceinline__ unsigned short f2bf(float f) {
    unsigned int u = __float_as_uint(f);
    u += 0x7FFFu + ((u >> 16) & 1u);   // RNE
    return (unsigned short)(u >> 16);
}
__device__ __forceinline__ float bf2f(unsigned short h) {
    return __uint_as_float(((unsigned int)h) << 16);
}

__device__ __forceinline__ void gld_lds16(const void* g, void* l) {
    __builtin_amdgcn_global_load_lds((const __attribute__((address_space(1))) void*)g,
                                     (__attribute__((address_space(3))) void*)l, 16, 0, 0);
}

// ---------------- transpose + f32->bf16 convert:  in [E][R][C] f32 -> out [E][C][R] bf16
__global__ __launch_bounds__(256) void transpose_cvt64(const float* __restrict__ in,
                                                       unsigned short* __restrict__ out,
                                                       int R, int C) {
    __shared__ float tile[64][65];
    int e = blockIdx.z;
    const float* ip = in + (size_t)e * R * C;
    unsigned short* op = out + (size_t)e * R * C;
    int c0 = blockIdx.x * 64, r0 = blockIdx.y * 64;
    int t = threadIdx.x;
#pragma unroll
    for (int i = 0; i < 4; i++) {
        int rr = i * 16 + (t >> 4);
        int cc = (t & 15) * 4;
        float4 v = *(const float4*)&ip[(size_t)(r0 + rr) * C + c0 + cc];
        tile[rr][cc] = v.x; tile[rr][cc + 1] = v.y; tile[rr][cc + 2] = v.z; tile[rr][cc + 3] = v.w;
    }
    __syncthreads();
    int c = t >> 2, rb = (t & 3) * 16;
    u16x8 o0, o1;
#pragma unroll
    for (int j = 0; j < 8; j++) o0[j] = f2bf(tile[rb + j][c]);
#pragma unroll
    for (int j = 0; j < 8; j++) o1[j] = f2bf(tile[rb + 8 + j][c]);
    unsigned short* dst = op + (size_t)(c0 + c) * R + r0 + rb;
    *(u16x8*)dst = o0;
    *(u16x8*)(dst + 8) = o1;
}

// ---------------- router: logits = x @ w_g, top-2 + softmax probs. One wave per token.
__global__ __launch_bounds__(256) void router_kernel(const float* __restrict__ x,
                                                     const float* __restrict__ wg,
                                                     int2* __restrict__ e01,
                                                     float2* __restrict__ p01) {
    int wid = threadIdx.x >> 6, lane = threadIdx.x & 63;
    int n = blockIdx.x * 4 + wid;
    float acc[8];
#pragma unroll
    for (int i = 0; i < 8; i++) acc[i] = 0.f;
    const float4* xr = (const float4*)(x + (size_t)n * DDIM);
#pragma unroll
    for (int j = 0; j < 4; j++) {
        float4 xv = xr[j * 64 + lane];
        int base = (j * 64 + lane) * 4;
        float xs[4] = {xv.x, xv.y, xv.z, xv.w};
#pragma unroll
        for (int t = 0; t < 4; t++) {
            const float4* wr = (const float4*)(wg + (size_t)(base + t) * 8);
            float4 w0 = wr[0], w1 = wr[1];
            acc[0] += xs[t] * w0.x; acc[1] += xs[t] * w0.y;
            acc[2] += xs[t] * w0.z; acc[3] += xs[t] * w0.w;
            acc[4] += xs[t] * w1.x; acc[5] += xs[t] * w1.y;
            acc[6] += xs[t] * w1.z; acc[7] += xs[t] * w1.w;
        }
    }
#pragma unroll
    for (int off = 32; off > 0; off >>= 1) {
#pragma unroll
        for (int i = 0; i < 8; i++) acc[i] += __shfl_xor(acc[i], off);
    }
    if (lane == 0) {
        int i0 = 0; float v0 = acc[0];
#pragma unroll
        for (int q = 1; q < 8; q++) { if (acc[q] > v0) { v0 = acc[q]; i0 = q; } }
        int i1 = -1; float v1 = -3.0e38f;
#pragma unroll
        for (int q = 0; q < 8; q++) { if (q != i0 && acc[q] > v1) { v1 = acc[q]; i1 = q; } }
        float ea = expf(v0 - v0), eb = expf(v1 - v0);
        float inv = 1.f / (ea + eb);
        e01[n] = make_int2(i0, i1);
        p01[n] = make_float2(ea * inv, eb * inv);
    }
}

// ---------------- assignment scan: exact reference ranks (all k=0 by token order, then k=1)
__global__ void assign_kernel(const int2* __restrict__ e01, int* __restrict__ counts,
                              int* __restrict__ assign_row, int* __restrict__ tok_slot) {
    int lane = threadIdx.x;   // single wave of 64
    int base[8];
#pragma unroll
    for (int i = 0; i < 8; i++) base[i] = 0;
    unsigned long long below = ((unsigned long long)1 << lane) - 1ull;
    int2 cur = e01[lane];
    for (int pass = 0; pass < 2; ++pass) {
        for (int t = 0; t < NTOK; t += 64) {
            int n = t + lane;
            int2 nxt;
            if (t + 64 < NTOK) nxt = e01[t + 64 + lane];
            else nxt = (pass == 0) ? e01[lane] : make_int2(0, 0);
            int ex = (pass == 0) ? cur.x : cur.y;
            int slot = -1;
#pragma unroll
            for (int q = 0; q < 8; q++) {
                unsigned long long m = __ballot(ex == q);
                if (ex == q) slot = base[q] + __popcll(m & below);
                base[q] += __popcll(m);
            }
            if (slot < CAP) {
                assign_row[ex * CAP + slot] = n;
                tok_slot[2 * n + pass] = slot;
            } else {
                tok_slot[2 * n + pass] = -1;
            }
            cur = nxt;
        }
    }
    if (lane < 8) counts[lane] = base[lane] > CAP ? CAP : base[lane];
}

// ---------------- gather x rows -> xg[e][slot][:] bf16. One wave per slot.
__global__ __launch_bounds__(256) void gather_rows(const float* __restrict__ x,
                                                   const int* __restrict__ assign_row,
                                                   const int* __restrict__ counts,
                                                   unsigned short* __restrict__ xg) {
    int e = blockIdx.y;
    int wid = threadIdx.x >> 6, lane = threadIdx.x & 63;
    int slot = blockIdx.x * 4 + wid;
    if (slot >= counts[e]) return;
    int n = assign_row[e * CAP + slot];
    const float4* src = (const float4*)(x + (size_t)n * DDIM);
    unsigned short* dst = xg + ((size_t)e * CAP + slot) * DDIM;
#pragma unroll
    for (int j = 0; j < 4; j++) {
        float4 v = src[j * 64 + lane];
        ushort4 o;
        o.x = f2bf(v.x); o.y = f2bf(v.y); o.z = f2bf(v.z); o.w = f2bf(v.w);
        *(ushort4*)(dst + (size_t)(j * 64 + lane) * 4) = o;
    }
}

// ---------------- R6-proven double-buffered 2-phase bf16 GEMM (best measured config):
// C[M,N] = A[M,K] * Bt[N,K]^T, f32 accum. BK=32, per-wave 64x64 (16x16x32 MFMA).
// WM x WN waves: fc 2x4 (BM=128,BN=256, 512thr, 48KB), proj 2x2 (BM=128,BN=128, 256thr, 32KB).
// Per K-tile: STAGE(t+1) FIRST, ds_read frags, MFMA, ONE __syncthreads (vmcnt0+lgkm
// drain hidden by co-resident blocks, m114 overlap).
// Swizzle (64B rows): 16B-col c ^= (row>>1)&3 both sides (0 conflicts, R6-R15).
// OBF: bf16 output (proj) — saves half the C-write + combine-read HBM traffic.
template <int WM, int WN, bool GELU, bool OBF>
__global__ __launch_bounds__(WM * WN * 64, 4) void gemm_db(const unsigned short* __restrict__ A,
                                                           const unsigned short* __restrict__ Bt,
                                                           void* __restrict__ Cout,
                                                           const int* __restrict__ counts,
                                                           int Mcap, int Ncols, int K) {
    constexpr int T = WM * WN * 64;
    constexpr int BM = WM * 64;
    constexpr int BN = WN * 64;
    constexpr int ABYTES = BM * 64;
    constexpr int BBYTES = BN * 64;
    constexpr int BUFB = ABYTES + BBYTES;
    constexpr int GA = (BM * 4) / T;
    constexpr int GB = (BN * 4) / T;
    __shared__ __align__(16) char smem[2 * BUFB];

    // T1: bijective chunked XCD swizzle (grid sizes are multiples of 8)
    int gx = gridDim.x, gy = gridDim.y;
    int nwg = gx * gy * gridDim.z;
    int flat = blockIdx.x + gx * (blockIdx.y + gy * blockIdx.z);
    int cpx = nwg >> 3;
    int swz = (flat & 7) * cpx + (flat >> 3);
    int gxy = gx * gy;
    int e  = swz / gxy;
    int r2 = swz - e * gxy;
    int by = r2 / gx;
    int bx = r2 - by * gx;

    int cnt = counts[e];
    int row0 = by * BM;
    if (row0 >= cnt) return;
    int col0 = bx * BN;

    int tid = threadIdx.x;
    int w = tid >> 6, lane = tid & 63;
    int wm = w / WN, wn = w % WN;

    const unsigned short* Ab = A + ((size_t)e * Mcap + row0) * K;
    const unsigned short* Bb = Bt + ((size_t)e * Ncols + col0) * K;
    int NT = K >> 5;

    // staging: chunk = i*T + tid; row = chunk>>2; source k-elem swizzled by
    // (tid&3)^((tid>>3)&3)  (== c ^ (row>>1)&3, since row=chunk>>2)
    int kel = (((tid & 3) ^ ((tid >> 3) & 3)) * 8);
    int rA = tid >> 2;          // + i*(T/4)
    int ldst = tid * 16;        // + i*T*16

    // swizzled read offsets (bytes within buffer)
    int a_off[4], b_off[4];
    int c = lane >> 4;
#pragma unroll
    for (int m = 0; m < 4; m++) {
        int row = wm * 64 + m * 16 + (lane & 15);
        a_off[m] = row * 64 + ((c ^ ((row >> 1) & 3)) * 16);
    }
#pragma unroll
    for (int n = 0; n < 4; n++) {
        int row = wn * 64 + n * 16 + (lane & 15);
        b_off[n] = row * 64 + ((c ^ ((row >> 1) & 3)) * 16);
    }

    auto stage = [&](int tt) {
        int bb = (tt & 1) * BUFB;
        size_t kt = (size_t)tt * 32 + kel;
#pragma unroll
        for (int i = 0; i < GA; i++)
            gld_lds16(Ab + (size_t)(i * (T / 4) + rA) * K + kt, smem + bb + i * T * 16 + ldst);
#pragma unroll
        for (int i = 0; i < GB; i++)
            gld_lds16(Bb + (size_t)(i * (T / 4) + rA) * K + kt, smem + bb + ABYTES + i * T * 16 + ldst);
    };

    f32x4 acc[4][4] = {};

    stage(0);
    __builtin_amdgcn_sched_barrier(0);
    __syncthreads();

    for (int t = 0; t < NT; ++t) {
        const int bb = (t & 1) * BUFB;
        if (t + 1 < NT) stage(t + 1);          // issue next-tile loads FIRST
        __builtin_amdgcn_sched_barrier(0);     // pin issue order
        bf16x8 af[4], bfr[4];
#pragma unroll
        for (int m = 0; m < 4; m++) af[m] = *(const bf16x8*)(smem + bb + a_off[m]);
#pragma unroll
        for (int n = 0; n < 4; n++) bfr[n] = *(const bf16x8*)(smem + bb + ABYTES + b_off[n]);
        __builtin_amdgcn_s_setprio(1);
#pragma unroll
        for (int m = 0; m < 4; m++)
#pragma unroll
            for (int n = 0; n < 4; n++)
                acc[m][n] = __builtin_amdgcn_mfma_f32_16x16x32_bf16(af[m], bfr[n], acc[m][n], 0, 0, 0);
        __builtin_amdgcn_s_setprio(0);
        __syncthreads();                        // ONE barrier/tile: drains vmcnt(0)+lgkm
    }

    // epilogue: C/D layout col = lane&15, row = (lane>>4)*4 + j
    unsigned short* Cb_h = (unsigned short*)Cout + ((size_t)e * Mcap + row0) * Ncols + col0;
    float* Cb_f = (float*)Cout + ((size_t)e * Mcap + row0) * Ncols + col0;
#pragma unroll
    for (int m = 0; m < 4; m++)
#pragma unroll
        for (int n = 0; n < 4; n++)
#pragma unroll
            for (int j = 0; j < 4; j++) {
                int lr = wm * 64 + m * 16 + ((lane >> 4) << 2) + j;
                int lc = wn * 64 + n * 16 + (lane & 15);
                float v = acc[m][n][j];
                if constexpr (GELU) {
                    float g = 0.5f * v * (1.0f + erff(v * 0.70710678118654752f));
                    Cb_h[(size_t)lr * Ncols + lc] = f2bf(g);
                } else if constexpr (OBF) {
                    Cb_h[(size_t)lr * Ncols + lc] = f2bf(v);
                } else {
                    Cb_f[(size_t)lr * Ncols + lc] = v;
                }
            }
}

// ---------------- combine (p0*eo0 + p1*eo1) + LayerNorm, one block per token. eo bf16.
__global__ __launch_bounds__(256) void combine_ln_kernel(const unsigned short* __restrict__ eo,
                                                         const int2* __restrict__ e01,
                                                         const float2* __restrict__ p01,
                                                         const int* __restrict__ tok_slot,
                                                         const float* __restrict__ lnw,
                                                         const float* __restrict__ lnb,
                                                         float* __restrict__ out) {
    int n = blockIdx.x, t = threadIdx.x;
    int2 e = e01[n];
    float2 p = p01[n];
    int s0 = tok_slot[2 * n], s1 = tok_slot[2 * n + 1];
    float o0 = 0.f, o1 = 0.f, o2 = 0.f, o3 = 0.f;
    if (s0 >= 0) {
        const ushort4* r = (const ushort4*)(eo + ((size_t)e.x * CAP + s0) * DDIM);
        ushort4 v = r[t];
        o0 += p.x * bf2f(v.x); o1 += p.x * bf2f(v.y); o2 += p.x * bf2f(v.z); o3 += p.x * bf2f(v.w);
    }
    if (s1 >= 0) {
        const ushort4* r = (const ushort4*)(eo + ((size_t)e.y * CAP + s1) * DDIM);
        ushort4 v = r[t];
        o0 += p.y * bf2f(v.x); o1 += p.y * bf2f(v.y); o2 += p.y * bf2f(v.z); o3 += p.y * bf2f(v.w);
    }
    float s = o0 + o1 + o2 + o3;
    float sq = o0 * o0 + o1 * o1 + o2 * o2 + o3 * o3;
#pragma unroll
    for (int off = 32; off > 0; off >>= 1) {
        s += __shfl_xor(s, off);
        sq += __shfl_xor(sq, off);
    }
    __shared__ float red[8];
    int wid = t >> 6, lane = t & 63;
    if (lane == 0) { red[wid] = s; red[4 + wid] = sq; }
    __syncthreads();
    s = red[0] + red[1] + red[2] + red[3];
    sq = red[4] + red[5] + red[6] + red[7];
    float mu = s * (1.f / DDIM);
    float var = sq * (1.f / DDIM) - mu * mu;
    float inv = rsqrtf(var + 1e-5f);
    const float4 w = ((const float4*)lnw)[t];
    const float4 b = ((const float4*)lnb)[t];
    float4 r;
    r.x = (o0 - mu) * inv * w.x + b.x;
    r.y = (o1 - mu) * inv * w.y + b.y;
    r.z = (o2 - mu) * inv * w.z + b.z;
    r.w = (o3 - mu) * inv * w.w + b.w;
    ((float4*)(out + (size_t)n * DDIM))[t] = r;
}

extern "C" void kernel_launch(void* const* d_in, const int* in_sizes, int n_in,
                              void* d_out, int out_size, void* d_ws, size_t ws_size,
                              hipStream_t stream) {
    const float* x   = (const float*)d_in[0];
    const float* wg  = (const float*)d_in[1];
    const float* cfc = (const float*)d_in[2];
    const float* cpr = (const float*)d_in[3];
    const float* lnw = (const float*)d_in[4];
    const float* lnb = (const float*)d_in[5];
    float* out = (float*)d_out;

    char* ws = (char*)d_ws;
    size_t off = 0;
    auto take = [&](size_t b) {
        char* p = ws + off;
        off += (b + 255) & ~(size_t)255;
        return p;
    };
    // c_fc_t [E][F][D] bf16 — dead after fc GEMM; eo [E][CAP][D] bf16 aliases it
    unsigned short* cfct = (unsigned short*)take((size_t)NEXP * FDIM * DDIM * 2);
    unsigned short* eo = cfct;
    unsigned short* cprt = (unsigned short*)take((size_t)NEXP * DDIM * FDIM * 2); // [E][D][F]
    unsigned short* xg   = (unsigned short*)take((size_t)NEXP * CAP * DDIM * 2);  // [E][CAP][D]
    unsigned short* h    = (unsigned short*)take((size_t)NEXP * CAP * FDIM * 2);  // [E][CAP][F]
    int2*   e01      = (int2*)take(NTOK * sizeof(int2));
    float2* p01      = (float2*)take(NTOK * sizeof(float2));
    int*    tok_slot = (int*)take((size_t)NTOK * 2 * 4);
    int*    assign_row = (int*)take((size_t)NEXP * CAP * 4);
    int*    counts   = (int*)take(256);

    transpose_cvt64<<<dim3(FDIM / 64, DDIM / 64, NEXP), 256, 0, stream>>>(cfc, cfct, DDIM, FDIM);
    transpose_cvt64<<<dim3(DDIM / 64, FDIM / 64, NEXP), 256, 0, stream>>>(cpr, cprt, FDIM, DDIM);
    router_kernel<<<NTOK / 4, 256, 0, stream>>>(x, wg, e01, p01);
    assign_kernel<<<1, 64, 0, stream>>>(e01, counts, assign_row, tok_slot);
    gather_rows<<<dim3(CAP / 4, NEXP), 256, 0, stream>>>(x, assign_row, counts, xg);
    // fc: BM=128, BN=256, 512 threads, 48KB LDS. grid 16x16x8 (best-measured config).
    gemm_db<2, 4, true,  false><<<dim3(FDIM / 256, CAP / 128, NEXP), 512, 0, stream>>>(xg, cfct, (void*)h, counts, CAP, FDIM, DDIM);
    // proj: BM=128, BN=128, 256 threads, 32KB LDS. grid 8x16x8. bf16 out (halves C-write traffic).
    gemm_db<2, 2, false, true ><<<dim3(DDIM / 128, CAP / 128, NEXP), 256, 0, stream>>>(h, cprt, (void*)eo, counts, CAP, DDIM, FDIM);
    combine_ln_kernel<<<NTOK, 256, 0, stream>>>(eo, e01, p01, tok_slot, lnw, lnb, out);
}